// Round 1
// baseline (1817.540 us; speedup 1.0000x reference)
//
#include <hip/hip_runtime.h>

typedef __attribute__((ext_vector_type(4))) float f32x4;
typedef __attribute__((ext_vector_type(8))) _Float16 f16x8;
typedef __attribute__((ext_vector_type(4))) _Float16 f16x4;

#define N_TOK 16384
#define DIM 1024
#define HID 2048
#define NE 8
#define CAP 4096

// ---------------- Router: scores^T (E, N) = softmax(x @ wg, axis=-1)^T -------
__global__ __launch_bounds__(256) void router_kernel(
    const float* __restrict__ x, const float* __restrict__ wg,
    float* __restrict__ scoresT)
{
    int t = blockIdx.x * 4 + (threadIdx.x >> 6);
    int lane = threadIdx.x & 63;
    const float* xr = x + (size_t)t * DIM;
    float acc[NE] = {};
    for (int k = lane; k < DIM; k += 64) {
        float xv = xr[k];
        const float4* w4 = (const float4*)(wg + (size_t)k * NE);
        float4 a = w4[0], b = w4[1];
        acc[0] += xv * a.x; acc[1] += xv * a.y; acc[2] += xv * a.z; acc[3] += xv * a.w;
        acc[4] += xv * b.x; acc[5] += xv * b.y; acc[6] += xv * b.z; acc[7] += xv * b.w;
    }
#pragma unroll
    for (int off = 32; off; off >>= 1)
#pragma unroll
        for (int e = 0; e < NE; ++e) acc[e] += __shfl_xor(acc[e], off);
    if (lane == 0) {
        float m = acc[0];
#pragma unroll
        for (int e = 1; e < NE; ++e) m = fmaxf(m, acc[e]);
        float p[NE]; float s = 0.f;
#pragma unroll
        for (int e = 0; e < NE; ++e) { p[e] = expf(acc[e] - m); s += p[e]; }
        float inv = 1.0f / s;
#pragma unroll
        for (int e = 0; e < NE; ++e) scoresT[(size_t)e * N_TOK + t] = p[e] * inv;
    }
}

// ------------- Radix-select per expert: exact 4096th-largest key ------------
__global__ __launch_bounds__(256) void topk_thresh_kernel(
    const float* __restrict__ scoresT, unsigned* __restrict__ Tkey,
    int* __restrict__ Gout, int* __restrict__ takeeq)
{
    int e = blockIdx.x;
    __shared__ int hist[256];
    __shared__ unsigned s_bin;
    __shared__ int s_cum;
    const float* row = scoresT + (size_t)e * N_TOK;
    unsigned prefix = 0, mask = 0;
    int remaining = CAP;
    for (int shift = 24; shift >= 0; shift -= 8) {
        hist[threadIdx.x] = 0;
        __syncthreads();
        for (int t = threadIdx.x; t < N_TOK; t += 256) {
            unsigned key = __float_as_uint(row[t]);
            if ((key & mask) == prefix) atomicAdd(&hist[(key >> shift) & 255], 1);
        }
        __syncthreads();
        if (threadIdx.x == 0) {
            int cum = 0; int b = 255;
            for (; b > 0; --b) {
                if (cum + hist[b] >= remaining) break;
                cum += hist[b];
            }
            s_bin = (unsigned)b;
            s_cum = cum;
        }
        __syncthreads();
        prefix |= (s_bin << shift);
        mask |= (255u << shift);
        remaining -= s_cum;
        __syncthreads();
    }
    if (threadIdx.x == 0) {
        Tkey[e] = prefix;
        takeeq[e] = remaining;            // # equal-to-threshold to take
        Gout[e] = CAP - remaining;        // # strictly greater
    }
}

// --------- Fill selected indices: strictly greater (order-free) -------------
__global__ __launch_bounds__(256) void fill_greater_kernel(
    const float* __restrict__ scoresT, const unsigned* __restrict__ Tkey,
    int* __restrict__ cnt, int* __restrict__ idx, float* __restrict__ scale)
{
    int t = blockIdx.x * 256 + threadIdx.x;
    int e = blockIdx.y;
    float s = scoresT[(size_t)e * N_TOK + t];
    if (__float_as_uint(s) > Tkey[e]) {
        int pos = atomicAdd(&cnt[e], 1);
        idx[e * CAP + pos] = t;
        scale[e * CAP + pos] = s;
    }
}

// --------- Fill ties deterministically by lowest token index ----------------
__global__ __launch_bounds__(256) void fill_equal_kernel(
    const float* __restrict__ scoresT, const unsigned* __restrict__ Tkey,
    const int* __restrict__ G, const int* __restrict__ takeeq,
    int* __restrict__ idx, float* __restrict__ scale)
{
    int t = blockIdx.x * 256 + threadIdx.x;
    int e = blockIdx.y;
    unsigned T = Tkey[e];
    if (__float_as_uint(scoresT[(size_t)e * N_TOK + t]) != T) return;
    int r = 0;
    for (int t2 = 0; t2 < t; ++t2)
        r += (__float_as_uint(scoresT[(size_t)e * N_TOK + t2]) == T) ? 1 : 0;
    if (r < takeeq[e]) {
        int pos = G[e] + r;
        idx[e * CAP + pos] = t;
        scale[e * CAP + pos] = __uint_as_float(T);
    }
}

// -------- Weight transpose+convert: (E,K,N) f32 -> (E,N,K) f16 --------------
__global__ __launch_bounds__(256) void transpose_convert_kernel(
    const float* __restrict__ W, _Float16* __restrict__ WT, int K, int N)
{
    int e = blockIdx.z;
    int k0 = blockIdx.x * 64;
    int n0 = blockIdx.y * 64;
    __shared__ float tile[64][65];
    const float* Wb = W + (size_t)e * K * N;
    _Float16* WTb = WT + (size_t)e * K * N;
#pragma unroll
    for (int i = 0; i < 16; ++i) {
        int lin = i * 256 + threadIdx.x;
        int r = lin >> 6, c = lin & 63;
        tile[r][c] = Wb[(size_t)(k0 + r) * N + n0 + c];
    }
    __syncthreads();
#pragma unroll
    for (int i = 0; i < 16; ++i) {
        int lin = i * 256 + threadIdx.x;
        int r = lin >> 6, c = lin & 63;   // r: n-offset, c: k-offset
        WTb[(size_t)(n0 + r) * K + k0 + c] = (_Float16)tile[c][r];
    }
}

// -------- Gather + scale + convert: A_e[c][d] = f16(x[idx[c]][d]*scale[c]) --
__global__ __launch_bounds__(256) void gather_rows_kernel(
    const float* __restrict__ x, const int* __restrict__ idxE,
    const float* __restrict__ scaleE, _Float16* __restrict__ Ae)
{
    int c = blockIdx.x;
    int token = idxE[c];
    float sc = scaleE[c];
    const float4* xr = (const float4*)(x + (size_t)token * DIM);
    float4 v = xr[threadIdx.x];
    f16x4 h;
    h[0] = (_Float16)(v.x * sc); h[1] = (_Float16)(v.y * sc);
    h[2] = (_Float16)(v.z * sc); h[3] = (_Float16)(v.w * sc);
    *(f16x4*)(Ae + (size_t)c * DIM + threadIdx.x * 4) = h;
}

// -------- SwiGLU elementwise: G1 <- silu(G1) * G3 (in place, f16) -----------
__global__ __launch_bounds__(256) void swiglu_kernel(
    _Float16* __restrict__ G1, const _Float16* __restrict__ G3)
{
    int i = blockIdx.x * 256 + threadIdx.x;
    f16x8 a = ((const f16x8*)G1)[i];
    f16x8 b = ((const f16x8*)G3)[i];
    f16x8 r;
#pragma unroll
    for (int j = 0; j < 8; ++j) {
        float g = (float)a[j];
        float s = g / (1.0f + __expf(-g));
        r[j] = (_Float16)(s * (float)b[j]);
    }
    ((f16x8*)G1)[i] = r;
}

// -------- GEMM: C(MxN) = A(MxK) @ Bt(NxK)^T, f16 in, fp32 acc ---------------
// MODE 0: store f16 to Cf16. MODE 1: atomicAdd fp32 rows scattered by rowidx.
template <int MODE>
__global__ __launch_bounds__(256) void gemm_bt_kernel(
    const _Float16* __restrict__ A, const _Float16* __restrict__ Bt,
    _Float16* __restrict__ Cf16, float* __restrict__ Cf32,
    const int* __restrict__ rowidx, int M, int N, int K)
{
    __shared__ _Float16 As[128][72];   // +8 halves pad: 2-way banks (free)
    __shared__ _Float16 Bs[128][72];
    const int bm = blockIdx.x * 128;
    const int bn = blockIdx.y * 128;
    const int tid = threadIdx.x;
    const int wave = tid >> 6, lane = tid & 63;
    const int wm = (wave >> 1) * 64, wn = (wave & 1) * 64;
    const int tr = tid >> 3;            // 0..31
    const int tc = (tid & 7) * 8;       // 0..56

    f32x4 acc[4][4] = {};
    const int row16 = lane & 15;
    const int q8 = (lane >> 4) * 8;

    for (int k0 = 0; k0 < K; k0 += 64) {
        __syncthreads();
#pragma unroll
        for (int i = 0; i < 4; ++i) {
            int r = tr + i * 32;
            *(uint4*)(&As[r][tc]) = *(const uint4*)(&A[(size_t)(bm + r) * K + k0 + tc]);
            *(uint4*)(&Bs[r][tc]) = *(const uint4*)(&Bt[(size_t)(bn + r) * K + k0 + tc]);
        }
        __syncthreads();
#pragma unroll
        for (int ks = 0; ks < 64; ks += 32) {
            f16x8 af[4], bf[4];
#pragma unroll
            for (int i = 0; i < 4; ++i) {
                af[i] = *(const f16x8*)(&As[wm + i * 16 + row16][ks + q8]);
                bf[i] = *(const f16x8*)(&Bs[wn + i * 16 + row16][ks + q8]);
            }
#pragma unroll
            for (int i = 0; i < 4; ++i)
#pragma unroll
                for (int j = 0; j < 4; ++j)
                    acc[i][j] = __builtin_amdgcn_mfma_f32_16x16x32_f16(
                        af[i], bf[j], acc[i][j], 0, 0, 0);
        }
    }

    const int col0 = lane & 15;
    const int r0 = (lane >> 4) * 4;
#pragma unroll
    for (int i = 0; i < 4; ++i) {
#pragma unroll
        for (int r = 0; r < 4; ++r) {
            int row = bm + wm + i * 16 + r0 + r;
            if (MODE == 0) {
#pragma unroll
                for (int j = 0; j < 4; ++j) {
                    int col = bn + wn + j * 16 + col0;
                    Cf16[(size_t)row * N + col] = (_Float16)acc[i][j][r];
                }
            } else {
                int token = rowidx[row];
#pragma unroll
                for (int j = 0; j < 4; ++j) {
                    int col = bn + wn + j * 16 + col0;
                    atomicAdd(&Cf32[(size_t)token * N + col], acc[i][j][r]);
                }
            }
        }
    }
}

extern "C" void kernel_launch(void* const* d_in, const int* in_sizes, int n_in,
                              void* d_out, int out_size, void* d_ws, size_t ws_size,
                              hipStream_t stream)
{
    const float* x  = (const float*)d_in[0];
    const float* wg = (const float*)d_in[1];
    const float* w1 = (const float*)d_in[2];
    const float* w3 = (const float*)d_in[3];
    const float* w2 = (const float*)d_in[4];
    float* out = (float*)d_out;

    char* ws = (char*)d_ws;
    size_t off = 0;
    auto alloc = [&](size_t bytes) -> void* {
        void* p = ws + off;
        off += (bytes + 255) & ~(size_t)255;
        return p;
    };
    float*     scoresT = (float*)alloc((size_t)NE * N_TOK * 4);
    unsigned*  Tkey    = (unsigned*)alloc(256);
    int*       Gc      = (int*)alloc(256);
    int*       takeeq  = (int*)alloc(256);
    int*       cnt     = (int*)alloc(256);
    int*       idx     = (int*)alloc((size_t)NE * CAP * 4);
    float*     scale   = (float*)alloc((size_t)NE * CAP * 4);
    _Float16*  w1T     = (_Float16*)alloc((size_t)NE * HID * DIM * 2);
    _Float16*  w3T     = (_Float16*)alloc((size_t)NE * HID * DIM * 2);
    _Float16*  w2T     = (_Float16*)alloc((size_t)NE * DIM * HID * 2);
    _Float16*  Ae      = (_Float16*)alloc((size_t)CAP * DIM * 2);
    _Float16*  G1      = (_Float16*)alloc((size_t)CAP * HID * 2);
    _Float16*  G3      = (_Float16*)alloc((size_t)CAP * HID * 2);

    hipMemsetAsync(d_out, 0, (size_t)out_size * 4, stream);
    hipMemsetAsync(cnt, 0, 256, stream);

    router_kernel<<<N_TOK / 4, 256, 0, stream>>>(x, wg, scoresT);
    topk_thresh_kernel<<<NE, 256, 0, stream>>>(scoresT, Tkey, Gc, takeeq);
    fill_greater_kernel<<<dim3(N_TOK / 256, NE), 256, 0, stream>>>(scoresT, Tkey, cnt, idx, scale);
    fill_equal_kernel<<<dim3(N_TOK / 256, NE), 256, 0, stream>>>(scoresT, Tkey, Gc, takeeq, idx, scale);

    transpose_convert_kernel<<<dim3(DIM / 64, HID / 64, NE), 256, 0, stream>>>(w1, w1T, DIM, HID);
    transpose_convert_kernel<<<dim3(DIM / 64, HID / 64, NE), 256, 0, stream>>>(w3, w3T, DIM, HID);
    transpose_convert_kernel<<<dim3(HID / 64, DIM / 64, NE), 256, 0, stream>>>(w2, w2T, HID, DIM);

    for (int e = 0; e < NE; ++e) {
        gather_rows_kernel<<<CAP, 256, 0, stream>>>(x, idx + e * CAP, scale + e * CAP, Ae);
        gemm_bt_kernel<0><<<dim3(CAP / 128, HID / 128), 256, 0, stream>>>(
            Ae, w1T + (size_t)e * HID * DIM, G1, nullptr, nullptr, CAP, HID, DIM);
        gemm_bt_kernel<0><<<dim3(CAP / 128, HID / 128), 256, 0, stream>>>(
            Ae, w3T + (size_t)e * HID * DIM, G3, nullptr, nullptr, CAP, HID, DIM);
        swiglu_kernel<<<(CAP * HID / 8) / 256, 256, 0, stream>>>(G1, G3);
        gemm_bt_kernel<1><<<dim3(CAP / 128, DIM / 128), 256, 0, stream>>>(
            G1, w2T + (size_t)e * DIM * HID, nullptr, out, idx + e * CAP, CAP, DIM, HID);
    }
}

// Round 2
// 1434.178 us; speedup vs baseline: 1.2673x; 1.2673x over previous
//
#include <hip/hip_runtime.h>

typedef __attribute__((ext_vector_type(4))) float f32x4;
typedef __attribute__((ext_vector_type(8))) _Float16 f16x8;
typedef __attribute__((ext_vector_type(4))) _Float16 f16x4;

#define N_TOK 16384
#define DIM 1024
#define HID 2048
#define NE 8
#define CAP 4096

// async global->LDS, 16B per lane; LDS dest is wave-uniform base + lane*16
#define GLD_LDS16(gaddr, laddr)                                                   \
    __builtin_amdgcn_global_load_lds(                                             \
        (const __attribute__((address_space(1))) void*)(gaddr),                   \
        (__attribute__((address_space(3))) void*)(laddr), 16, 0, 0)

// ---------------- Router: scores^T (E, N) = softmax(x @ wg, axis=-1)^T -------
__global__ __launch_bounds__(256) void router_kernel(
    const float* __restrict__ x, const float* __restrict__ wg,
    float* __restrict__ scoresT)
{
    int t = blockIdx.x * 4 + (threadIdx.x >> 6);
    int lane = threadIdx.x & 63;
    const float* xr = x + (size_t)t * DIM;
    float acc[NE] = {};
    for (int k = lane; k < DIM; k += 64) {
        float xv = xr[k];
        const float4* w4 = (const float4*)(wg + (size_t)k * NE);
        float4 a = w4[0], b = w4[1];
        acc[0] += xv * a.x; acc[1] += xv * a.y; acc[2] += xv * a.z; acc[3] += xv * a.w;
        acc[4] += xv * b.x; acc[5] += xv * b.y; acc[6] += xv * b.z; acc[7] += xv * b.w;
    }
#pragma unroll
    for (int off = 32; off; off >>= 1)
#pragma unroll
        for (int e = 0; e < NE; ++e) acc[e] += __shfl_xor(acc[e], off);
    if (lane == 0) {
        float m = acc[0];
#pragma unroll
        for (int e = 1; e < NE; ++e) m = fmaxf(m, acc[e]);
        float p[NE]; float s = 0.f;
#pragma unroll
        for (int e = 0; e < NE; ++e) { p[e] = expf(acc[e] - m); s += p[e]; }
        float inv = 1.0f / s;
#pragma unroll
        for (int e = 0; e < NE; ++e) scoresT[(size_t)e * N_TOK + t] = p[e] * inv;
    }
}

// ------------- Radix-select per expert: exact 4096th-largest key ------------
__global__ __launch_bounds__(256) void topk_thresh_kernel(
    const float* __restrict__ scoresT, unsigned* __restrict__ Tkey,
    int* __restrict__ Gout, int* __restrict__ takeeq)
{
    int e = blockIdx.x;
    __shared__ int hist[256];
    __shared__ unsigned s_bin;
    __shared__ int s_cum;
    const float* row = scoresT + (size_t)e * N_TOK;
    unsigned prefix = 0, mask = 0;
    int remaining = CAP;
    for (int shift = 24; shift >= 0; shift -= 8) {
        hist[threadIdx.x] = 0;
        __syncthreads();
        for (int t = threadIdx.x; t < N_TOK; t += 256) {
            unsigned key = __float_as_uint(row[t]);
            if ((key & mask) == prefix) atomicAdd(&hist[(key >> shift) & 255], 1);
        }
        __syncthreads();
        if (threadIdx.x == 0) {
            int cum = 0; int b = 255;
            for (; b > 0; --b) {
                if (cum + hist[b] >= remaining) break;
                cum += hist[b];
            }
            s_bin = (unsigned)b;
            s_cum = cum;
        }
        __syncthreads();
        prefix |= (s_bin << shift);
        mask |= (255u << shift);
        remaining -= s_cum;
        __syncthreads();
    }
    if (threadIdx.x == 0) {
        Tkey[e] = prefix;
        takeeq[e] = remaining;            // # equal-to-threshold to take
        Gout[e] = CAP - remaining;        // # strictly greater
    }
}

// --- One pass: fill strictly-greater (order-free) + collect tie candidates --
__global__ __launch_bounds__(256) void fill_select_kernel(
    const float* __restrict__ scoresT, const unsigned* __restrict__ Tkey,
    int* __restrict__ cnt, int* __restrict__ tiecnt,
    int* __restrict__ idx, float* __restrict__ scale, int* __restrict__ tiebuf)
{
    int t = blockIdx.x * 256 + threadIdx.x;
    int e = blockIdx.y;
    float s = scoresT[(size_t)e * N_TOK + t];
    unsigned key = __float_as_uint(s);
    unsigned T = Tkey[e];
    if (key > T) {
        int pos = atomicAdd(&cnt[e], 1);
        idx[e * CAP + pos] = t;
        scale[e * CAP + pos] = s;
    } else if (key == T) {
        int pos = atomicAdd(&tiecnt[e], 1);
        tiebuf[e * N_TOK + pos] = t;
    }
}

// --- Rank ties in parallel, keep lowest-index takeeq of them ---------------
__global__ __launch_bounds__(256) void tie_rank_kernel(
    const unsigned* __restrict__ Tkey, const int* __restrict__ G,
    const int* __restrict__ takeeq, const int* __restrict__ tiecnt,
    const int* __restrict__ tiebuf, int* __restrict__ idx, float* __restrict__ scale)
{
    int e = blockIdx.x;
    int T = tiecnt[e];
    int q = takeeq[e];
    int g = G[e];
    float sv = __uint_as_float(Tkey[e]);
    const int* tb = tiebuf + (size_t)e * N_TOK;
    for (int i = threadIdx.x; i < T; i += 256) {
        int my = tb[i];
        int rank = 0;
        for (int j = 0; j < T; ++j) rank += (tb[j] < my) ? 1 : 0;
        if (rank < q) {
            idx[e * CAP + g + rank] = my;
            scale[e * CAP + g + rank] = sv;
        }
    }
}

// -------- Weight transpose+convert: (E,K,N) f32 -> (E,N,K) f16 --------------
__global__ __launch_bounds__(256) void transpose_convert_kernel(
    const float* __restrict__ W, _Float16* __restrict__ WT, int K, int N)
{
    int e = blockIdx.z;
    int k0 = blockIdx.x * 64;
    int n0 = blockIdx.y * 64;
    __shared__ float tile[64][65];
    const float* Wb = W + (size_t)e * K * N;
    _Float16* WTb = WT + (size_t)e * K * N;
#pragma unroll
    for (int i = 0; i < 16; ++i) {
        int lin = i * 256 + threadIdx.x;
        int r = lin >> 6, c = lin & 63;
        tile[r][c] = Wb[(size_t)(k0 + r) * N + n0 + c];
    }
    __syncthreads();
#pragma unroll
    for (int i = 0; i < 16; ++i) {
        int lin = i * 256 + threadIdx.x;
        int r = lin >> 6, c = lin & 63;   // r: n-offset, c: k-offset
        WTb[(size_t)(n0 + r) * K + k0 + c] = (_Float16)tile[c][r];
    }
}

// -------- Gather + scale + convert: A_e[c][d] = f16(x[idx[c]][d]*scale[c]) --
__global__ __launch_bounds__(256) void gather_rows_kernel(
    const float* __restrict__ x, const int* __restrict__ idxE,
    const float* __restrict__ scaleE, _Float16* __restrict__ Ae)
{
    int c = blockIdx.x;
    int token = idxE[c];
    float sc = scaleE[c];
    const float4* xr = (const float4*)(x + (size_t)token * DIM);
    float4 v = xr[threadIdx.x];
    f16x4 h;
    h[0] = (_Float16)(v.x * sc); h[1] = (_Float16)(v.y * sc);
    h[2] = (_Float16)(v.z * sc); h[3] = (_Float16)(v.w * sc);
    *(f16x4*)(Ae + (size_t)c * DIM + threadIdx.x * 4) = h;
}

// -------- SwiGLU elementwise: G1 <- silu(G1) * G3 (in place, f16) -----------
__global__ __launch_bounds__(256) void swiglu_kernel(
    _Float16* __restrict__ G1, const _Float16* __restrict__ G3)
{
    int i = blockIdx.x * 256 + threadIdx.x;
    f16x8 a = ((const f16x8*)G1)[i];
    f16x8 b = ((const f16x8*)G3)[i];
    f16x8 r;
#pragma unroll
    for (int j = 0; j < 8; ++j) {
        float g = (float)a[j];
        float s = g / (1.0f + __expf(-g));
        r[j] = (_Float16)(s * (float)b[j]);
    }
    ((f16x8*)G1)[i] = r;
}

// -------- GEMM: C(MxN) = A(MxK) @ Bt(NxK)^T, f16 in, fp32 acc ---------------
// m97-style: global_load_lds width-16 staging, unpadded 128x64 LDS tiles.
// MODE 0: store f16 to Cf16. MODE 1: atomicAdd fp32 rows scattered by rowidx.
template <int MODE>
__global__ __launch_bounds__(256) void gemm_bt_kernel(
    const _Float16* __restrict__ A, const _Float16* __restrict__ Bt,
    _Float16* __restrict__ Cf16, float* __restrict__ Cf32,
    const int* __restrict__ rowidx, int M, int N, int K)
{
    __shared__ _Float16 As[128 * 64];   // row-major, 64-half rows (no pad: glds needs contiguity)
    __shared__ _Float16 Bs[128 * 64];
    const int bm = blockIdx.x * 128;
    const int bn = blockIdx.y * 128;
    const int tid = threadIdx.x;
    const int wave = tid >> 6, lane = tid & 63;
    const int wm = (wave >> 1) * 64, wn = (wave & 1) * 64;
    // staging map: chunk = 8 rows x 64 halves = 1 KiB; lane covers row lr, cols lc..lc+7
    const int lr = lane >> 3;           // 0..7
    const int lc = (lane & 7) * 8;      // 0..56

    f32x4 acc[4][4] = {};
    const int row16 = lane & 15;
    const int q8 = (lane >> 4) * 8;

    const _Float16* gA = A + (size_t)(bm + wave * 32 + lr) * K + lc;
    const _Float16* gB = Bt + (size_t)(bn + wave * 32 + lr) * K + lc;
    _Float16* lA = As + (wave * 32) * 64;   // wave-uniform LDS chunk bases
    _Float16* lB = Bs + (wave * 32) * 64;

    for (int k0 = 0; k0 < K; k0 += 64) {
        __syncthreads();
#pragma unroll
        for (int i = 0; i < 4; ++i) {
            GLD_LDS16(gA + (size_t)i * 8 * K + k0, lA + i * 8 * 64);
            GLD_LDS16(gB + (size_t)i * 8 * K + k0, lB + i * 8 * 64);
        }
        __syncthreads();
#pragma unroll
        for (int ks = 0; ks < 64; ks += 32) {
            f16x8 af[4], bf[4];
#pragma unroll
            for (int i = 0; i < 4; ++i) {
                af[i] = *(const f16x8*)(&As[(wm + i * 16 + row16) * 64 + ks + q8]);
                bf[i] = *(const f16x8*)(&Bs[(wn + i * 16 + row16) * 64 + ks + q8]);
            }
#pragma unroll
            for (int i = 0; i < 4; ++i)
#pragma unroll
                for (int j = 0; j < 4; ++j)
                    acc[i][j] = __builtin_amdgcn_mfma_f32_16x16x32_f16(
                        af[i], bf[j], acc[i][j], 0, 0, 0);
        }
    }

    const int col0 = lane & 15;
    const int r0 = (lane >> 4) * 4;
#pragma unroll
    for (int i = 0; i < 4; ++i) {
#pragma unroll
        for (int r = 0; r < 4; ++r) {
            int row = bm + wm + i * 16 + r0 + r;
            if (MODE == 0) {
#pragma unroll
                for (int j = 0; j < 4; ++j) {
                    int col = bn + wn + j * 16 + col0;
                    Cf16[(size_t)row * N + col] = (_Float16)acc[i][j][r];
                }
            } else {
                int token = rowidx[row];
#pragma unroll
                for (int j = 0; j < 4; ++j) {
                    int col = bn + wn + j * 16 + col0;
                    atomicAdd(&Cf32[(size_t)token * N + col], acc[i][j][r]);
                }
            }
        }
    }
}

extern "C" void kernel_launch(void* const* d_in, const int* in_sizes, int n_in,
                              void* d_out, int out_size, void* d_ws, size_t ws_size,
                              hipStream_t stream)
{
    const float* x  = (const float*)d_in[0];
    const float* wg = (const float*)d_in[1];
    const float* w1 = (const float*)d_in[2];
    const float* w3 = (const float*)d_in[3];
    const float* w2 = (const float*)d_in[4];
    float* out = (float*)d_out;

    char* ws = (char*)d_ws;
    size_t off = 0;
    auto alloc = [&](size_t bytes) -> void* {
        void* p = ws + off;
        off += (bytes + 255) & ~(size_t)255;
        return p;
    };
    float*     scoresT  = (float*)alloc((size_t)NE * N_TOK * 4);
    unsigned*  Tkey     = (unsigned*)alloc(256);
    int*       Gc       = (int*)alloc(256);
    int*       takeeq   = (int*)alloc(256);
    int*       counters = (int*)alloc(256);      // [0..7]=cnt, [8..15]=tiecnt
    int*       idx      = (int*)alloc((size_t)NE * CAP * 4);
    float*     scale    = (float*)alloc((size_t)NE * CAP * 4);
    int*       tiebuf   = (int*)alloc((size_t)NE * N_TOK * 4);
    _Float16*  w1T      = (_Float16*)alloc((size_t)NE * HID * DIM * 2);
    _Float16*  w3T      = (_Float16*)alloc((size_t)NE * HID * DIM * 2);
    _Float16*  w2T      = (_Float16*)alloc((size_t)NE * DIM * HID * 2);
    _Float16*  Ae       = (_Float16*)alloc((size_t)CAP * DIM * 2);
    _Float16*  G1       = (_Float16*)alloc((size_t)CAP * HID * 2);
    _Float16*  G3       = (_Float16*)alloc((size_t)CAP * HID * 2);
    int* cnt = counters;
    int* tiecnt = counters + 8;

    hipMemsetAsync(d_out, 0, (size_t)out_size * 4, stream);
    hipMemsetAsync(counters, 0, 256, stream);

    router_kernel<<<N_TOK / 4, 256, 0, stream>>>(x, wg, scoresT);
    topk_thresh_kernel<<<NE, 256, 0, stream>>>(scoresT, Tkey, Gc, takeeq);
    fill_select_kernel<<<dim3(N_TOK / 256, NE), 256, 0, stream>>>(
        scoresT, Tkey, cnt, tiecnt, idx, scale, tiebuf);
    tie_rank_kernel<<<NE, 256, 0, stream>>>(Tkey, Gc, takeeq, tiecnt, tiebuf, idx, scale);

    transpose_convert_kernel<<<dim3(DIM / 64, HID / 64, NE), 256, 0, stream>>>(w1, w1T, DIM, HID);
    transpose_convert_kernel<<<dim3(DIM / 64, HID / 64, NE), 256, 0, stream>>>(w3, w3T, DIM, HID);
    transpose_convert_kernel<<<dim3(HID / 64, DIM / 64, NE), 256, 0, stream>>>(w2, w2T, HID, DIM);

    for (int e = 0; e < NE; ++e) {
        gather_rows_kernel<<<CAP, 256, 0, stream>>>(x, idx + e * CAP, scale + e * CAP, Ae);
        gemm_bt_kernel<0><<<dim3(CAP / 128, HID / 128), 256, 0, stream>>>(
            Ae, w1T + (size_t)e * HID * DIM, G1, nullptr, nullptr, CAP, HID, DIM);
        gemm_bt_kernel<0><<<dim3(CAP / 128, HID / 128), 256, 0, stream>>>(
            Ae, w3T + (size_t)e * HID * DIM, G3, nullptr, nullptr, CAP, HID, DIM);
        swiglu_kernel<<<(CAP * HID / 8) / 256, 256, 0, stream>>>(G1, G3);
        gemm_bt_kernel<1><<<dim3(CAP / 128, DIM / 128), 256, 0, stream>>>(
            G1, w2T + (size_t)e * DIM * HID, nullptr, out, idx + e * CAP, CAP, DIM, HID);
    }
}

// Round 3
// 1338.550 us; speedup vs baseline: 1.3578x; 1.0714x over previous
//
#include <hip/hip_runtime.h>

typedef __attribute__((ext_vector_type(4))) float f32x4;
typedef __attribute__((ext_vector_type(8))) _Float16 f16x8;
typedef __attribute__((ext_vector_type(4))) _Float16 f16x4;

#define N_TOK 16384
#define DIM 1024
#define HID 2048
#define NE 8
#define CAP 4096

// async global->LDS, 16B per lane; LDS dest is wave-uniform base + lane*16
#define GLD_LDS16(gaddr, laddr)                                                   \
    __builtin_amdgcn_global_load_lds(                                             \
        (const __attribute__((address_space(1))) void*)(gaddr),                   \
        (__attribute__((address_space(3))) void*)(laddr), 16, 0, 0)

// ---------------- Router: scores^T (E, N) = softmax(x @ wg, axis=-1)^T -------
__global__ __launch_bounds__(256) void router_kernel(
    const float* __restrict__ x, const float* __restrict__ wg,
    float* __restrict__ scoresT)
{
    int t = blockIdx.x * 4 + (threadIdx.x >> 6);
    int lane = threadIdx.x & 63;
    const float* xr = x + (size_t)t * DIM;
    float acc[NE] = {};
    for (int k = lane; k < DIM; k += 64) {
        float xv = xr[k];
        const float4* w4 = (const float4*)(wg + (size_t)k * NE);
        float4 a = w4[0], b = w4[1];
        acc[0] += xv * a.x; acc[1] += xv * a.y; acc[2] += xv * a.z; acc[3] += xv * a.w;
        acc[4] += xv * b.x; acc[5] += xv * b.y; acc[6] += xv * b.z; acc[7] += xv * b.w;
    }
#pragma unroll
    for (int off = 32; off; off >>= 1)
#pragma unroll
        for (int e = 0; e < NE; ++e) acc[e] += __shfl_xor(acc[e], off);
    if (lane == 0) {
        float m = acc[0];
#pragma unroll
        for (int e = 1; e < NE; ++e) m = fmaxf(m, acc[e]);
        float p[NE]; float s = 0.f;
#pragma unroll
        for (int e = 0; e < NE; ++e) { p[e] = expf(acc[e] - m); s += p[e]; }
        float inv = 1.0f / s;
#pragma unroll
        for (int e = 0; e < NE; ++e) scoresT[(size_t)e * N_TOK + t] = p[e] * inv;
    }
}

// ---- Top-k pass 1: global 65536-bin histogram of top-16 key bits ----------
__global__ __launch_bounds__(256) void hist16_kernel(
    const float* __restrict__ scoresT, int* __restrict__ hist)
{
    int e = blockIdx.y;
    int t = blockIdx.x * 512 + threadIdx.x;
    const float* row = scoresT + (size_t)e * N_TOK;
    int* h = hist + (size_t)e * 65536;
#pragma unroll
    for (int i = 0; i < 2; ++i) {
        unsigned key = __float_as_uint(row[t + i * 256]);
        atomicAdd(&h[key >> 16], 1);
    }
}

// ---- Top-k pass 2: find threshold bin, strictly-above count, remaining ----
__global__ __launch_bounds__(256) void scan16_kernel(
    const int* __restrict__ hist, unsigned* __restrict__ prefix16,
    int* __restrict__ G16, int* __restrict__ rem)
{
    int e = blockIdx.x;
    const int* h = hist + (size_t)e * 65536;
    __shared__ int sums[256];
    __shared__ int bins[256];
    __shared__ int s_c, s_cum;
    int t = threadIdx.x;
    int s = 0;
    for (int b = 0; b < 256; ++b) s += h[t * 256 + b];
    sums[t] = s;
    __syncthreads();
    if (t == 0) {
        int cum = 0; int c = 255;
        for (; c >= 0; --c) {
            if (cum + sums[c] >= CAP) break;
            cum += sums[c];
        }
        s_c = c; s_cum = cum;
    }
    __syncthreads();
    bins[t] = h[s_c * 256 + t];
    __syncthreads();
    if (t == 0) {
        int cum = s_cum; int b = 255;
        for (; b >= 0; --b) {
            if (cum + bins[b] >= CAP) break;
            cum += bins[b];
        }
        prefix16[e] = (unsigned)(s_c * 256 + b);
        G16[e] = cum;            // strictly above threshold bin
        rem[e] = CAP - cum;      // to take from within the bin
    }
}

// ---- Top-k pass 3: fill strictly-above (order-free) + collect bin members -
__global__ __launch_bounds__(256) void fill_collect_kernel(
    const float* __restrict__ scoresT, const unsigned* __restrict__ prefix16,
    int* __restrict__ cnt, int* __restrict__ candcnt,
    int* __restrict__ idx, float* __restrict__ scale, unsigned* __restrict__ candbuf)
{
    int t = blockIdx.x * 256 + threadIdx.x;
    int e = blockIdx.y;
    float s = scoresT[(size_t)e * N_TOK + t];
    unsigned hi = __float_as_uint(s) >> 16;
    unsigned p16 = prefix16[e];
    if (hi > p16) {
        int pos = atomicAdd(&cnt[e], 1);
        idx[e * CAP + pos] = t;
        scale[e * CAP + pos] = s;
    } else if (hi == p16) {
        int pos = atomicAdd(&candcnt[e], 1);
        // descending order of packed = key desc, then token asc (top_k ties)
        candbuf[(size_t)e * N_TOK + pos] =
            ((__float_as_uint(s) & 0xFFFFu) << 16) | (unsigned)(16383 - t);
    }
}

// ---- Top-k pass 4: rank in-bin candidates, keep top `rem` ------------------
__global__ __launch_bounds__(256) void cand_rank_kernel(
    const unsigned* __restrict__ prefix16, const int* __restrict__ G16,
    const int* __restrict__ rem, const int* __restrict__ candcnt,
    const unsigned* __restrict__ candbuf, int* __restrict__ idx, float* __restrict__ scale)
{
    int e = blockIdx.x;
    int Tc = candcnt[e], q = rem[e], g = G16[e];
    const unsigned* cb = candbuf + (size_t)e * N_TOK;
    for (int i = threadIdx.x; i < Tc; i += 256) {
        unsigned mine = cb[i];
        int rank = 0;
        for (int j = 0; j < Tc; ++j) rank += (cb[j] > mine) ? 1 : 0;
        if (rank < q) {
            int token = 16383 - (int)(mine & 0xFFFFu);
            unsigned keyfull = (prefix16[e] << 16) | (mine >> 16);
            idx[e * CAP + g + rank] = token;
            scale[e * CAP + g + rank] = __uint_as_float(keyfull);
        }
    }
}

// -------- Weight transpose+convert: (E,K,N) f32 -> rows at WT+e*ostride+n*K -
__global__ __launch_bounds__(256) void transpose_convert_kernel(
    const float* __restrict__ W, _Float16* __restrict__ WT, int K, int N,
    size_t ostride)
{
    int e = blockIdx.z;
    int k0 = blockIdx.x * 64;
    int n0 = blockIdx.y * 64;
    __shared__ float tile[64][65];
    const float* Wb = W + (size_t)e * K * N;
    _Float16* WTb = WT + (size_t)e * ostride;
#pragma unroll
    for (int i = 0; i < 16; ++i) {
        int lin = i * 256 + threadIdx.x;
        int r = lin >> 6, c = lin & 63;
        tile[r][c] = Wb[(size_t)(k0 + r) * N + n0 + c];
    }
    __syncthreads();
#pragma unroll
    for (int i = 0; i < 16; ++i) {
        int lin = i * 256 + threadIdx.x;
        int r = lin >> 6, c = lin & 63;   // r: n-offset, c: k-offset
        WTb[(size_t)(n0 + r) * K + k0 + c] = (_Float16)tile[c][r];
    }
}

// -------- Gather + scale + convert: A_e[c][d] = f16(x[idx[c]][d]*scale[c]) --
__global__ __launch_bounds__(256) void gather_rows_kernel(
    const float* __restrict__ x, const int* __restrict__ idxE,
    const float* __restrict__ scaleE, _Float16* __restrict__ Ae)
{
    int c = blockIdx.x;
    int token = idxE[c];
    float sc = scaleE[c];
    const float4* xr = (const float4*)(x + (size_t)token * DIM);
    float4 v = xr[threadIdx.x];
    f16x4 h;
    h[0] = (_Float16)(v.x * sc); h[1] = (_Float16)(v.y * sc);
    h[2] = (_Float16)(v.z * sc); h[3] = (_Float16)(v.w * sc);
    *(f16x4*)(Ae + (size_t)c * DIM + threadIdx.x * 4) = h;
}

// -------- SwiGLU: G[c][h] <- silu(G[c][h]) * G[c][2048+h], in place ---------
__global__ __launch_bounds__(256) void swiglu_kernel(_Float16* __restrict__ G)
{
    int i = blockIdx.x * 256 + threadIdx.x;   // over CAP * (HID/8)
    int c = i >> 8;                            // HID/8 = 256
    int h8 = (i & 255) * 8;
    _Float16* ga = G + (size_t)c * 4096 + h8;
    f16x8 a = *(const f16x8*)ga;
    f16x8 b = *(const f16x8*)(ga + HID);
    f16x8 r;
#pragma unroll
    for (int j = 0; j < 8; ++j) {
        float g = (float)a[j];
        float s = g / (1.0f + __expf(-g));
        r[j] = (_Float16)(s * (float)b[j]);
    }
    *(f16x8*)ga = r;
}

// -------- GEMM: C(MxN) = A(MxK,lda) @ Bt(NxK)^T, f16 in, fp32 acc -----------
// global_load_lds width-16 staging + XOR-swizzled LDS (conflict-free reads).
// MODE 0: store f16 to Cf16. MODE 1: atomicAdd fp32 rows scattered by rowidx.
template <int MODE>
__global__ __launch_bounds__(256) void gemm_bt_kernel(
    const _Float16* __restrict__ A, const _Float16* __restrict__ Bt,
    _Float16* __restrict__ Cf16, float* __restrict__ Cf32,
    const int* __restrict__ rowidx, int M, int N, int K, int lda)
{
    __shared__ _Float16 As[128 * 64];
    __shared__ _Float16 Bs[128 * 64];
    const int bm = blockIdx.x * 128;
    const int bn = blockIdx.y * 128;
    const int tid = threadIdx.x;
    const int wave = tid >> 6, lane = tid & 63;
    const int wm = (wave >> 1) * 64, wn = (wave & 1) * 64;
    // staging: chunk = 8 rows x 64 halves; lane lr=row, fetches col-group
    // (lane&7)^lr so that LDS physical chunk (row r, cg p) holds logical
    // col-group p^(r&7)  -> readers use cg_phys = cg_log ^ (row&7)
    const int lr = lane >> 3;                    // 0..7
    const int lcs = ((lane & 7) ^ lr) * 8;       // swizzled col start (halves)

    f32x4 acc[4][4] = {};
    const int row16 = lane & 15;
    const int qi = lane >> 4;                    // 0..3
    const int r7 = row16 & 7;

    const _Float16* gA = A + (size_t)(bm + wave * 32 + lr) * lda + lcs;
    const _Float16* gB = Bt + (size_t)(bn + wave * 32 + lr) * K + lcs;
    _Float16* lA = As + (wave * 32) * 64;        // wave-uniform LDS chunk bases
    _Float16* lB = Bs + (wave * 32) * 64;

    for (int k0 = 0; k0 < K; k0 += 64) {
        __syncthreads();
#pragma unroll
        for (int i = 0; i < 4; ++i) {
            GLD_LDS16(gA + (size_t)i * 8 * lda + k0, lA + i * 8 * 64);
            GLD_LDS16(gB + (size_t)i * 8 * K + k0, lB + i * 8 * 64);
        }
        __syncthreads();
#pragma unroll
        for (int ks = 0; ks < 64; ks += 32) {
            const int kc = ks >> 3;
            f16x8 af[4], bf[4];
#pragma unroll
            for (int i = 0; i < 4; ++i) {
                af[i] = *(const f16x8*)(&As[(wm + i * 16 + row16) * 64 +
                                            (((kc + qi) ^ r7) << 3)]);
                bf[i] = *(const f16x8*)(&Bs[(wn + i * 16 + row16) * 64 +
                                            (((kc + qi) ^ r7) << 3)]);
            }
#pragma unroll
            for (int i = 0; i < 4; ++i)
#pragma unroll
                for (int j = 0; j < 4; ++j)
                    acc[i][j] = __builtin_amdgcn_mfma_f32_16x16x32_f16(
                        af[i], bf[j], acc[i][j], 0, 0, 0);
        }
    }

    const int col0 = lane & 15;
    const int r0 = (lane >> 4) * 4;
#pragma unroll
    for (int i = 0; i < 4; ++i) {
#pragma unroll
        for (int r = 0; r < 4; ++r) {
            int row = bm + wm + i * 16 + r0 + r;
            if (MODE == 0) {
#pragma unroll
                for (int j = 0; j < 4; ++j) {
                    int col = bn + wn + j * 16 + col0;
                    Cf16[(size_t)row * N + col] = (_Float16)acc[i][j][r];
                }
            } else {
                int token = rowidx[row];
#pragma unroll
                for (int j = 0; j < 4; ++j) {
                    int col = bn + wn + j * 16 + col0;
                    atomicAdd(&Cf32[(size_t)token * N + col], acc[i][j][r]);
                }
            }
        }
    }
}

extern "C" void kernel_launch(void* const* d_in, const int* in_sizes, int n_in,
                              void* d_out, int out_size, void* d_ws, size_t ws_size,
                              hipStream_t stream)
{
    const float* x  = (const float*)d_in[0];
    const float* wg = (const float*)d_in[1];
    const float* w1 = (const float*)d_in[2];
    const float* w3 = (const float*)d_in[3];
    const float* w2 = (const float*)d_in[4];
    float* out = (float*)d_out;

    char* ws = (char*)d_ws;
    size_t off = 0;
    auto alloc = [&](size_t bytes) -> void* {
        void* p = ws + off;
        off += (bytes + 255) & ~(size_t)255;
        return p;
    };
    float*     scoresT  = (float*)alloc((size_t)NE * N_TOK * 4);
    int*       hist     = (int*)alloc((size_t)NE * 65536 * 4);     // 2 MB
    unsigned*  prefix16 = (unsigned*)alloc(256);
    int*       G16      = (int*)alloc(256);
    int*       rem      = (int*)alloc(256);
    int*       counters = (int*)alloc(256);      // [0..7]=cnt, [8..15]=candcnt
    int*       idx      = (int*)alloc((size_t)NE * CAP * 4);
    float*     scale    = (float*)alloc((size_t)NE * CAP * 4);
    unsigned*  candbuf  = (unsigned*)alloc((size_t)NE * N_TOK * 4);
    _Float16*  w13T     = (_Float16*)alloc((size_t)NE * 2 * HID * DIM * 2); // 64 MB
    _Float16*  w2T      = (_Float16*)alloc((size_t)NE * DIM * HID * 2);     // 32 MB
    _Float16*  Ae       = (_Float16*)alloc((size_t)CAP * DIM * 2);
    _Float16*  G        = (_Float16*)alloc((size_t)CAP * 2 * HID * 2);      // 32 MB
    int* cnt = counters;
    int* candcnt = counters + 8;
    const size_t W13_STRIDE = (size_t)2 * HID * DIM;   // per-expert, halves

    hipMemsetAsync(d_out, 0, (size_t)out_size * 4, stream);
    hipMemsetAsync(counters, 0, 256, stream);
    hipMemsetAsync(hist, 0, (size_t)NE * 65536 * 4, stream);

    router_kernel<<<N_TOK / 4, 256, 0, stream>>>(x, wg, scoresT);
    hist16_kernel<<<dim3(N_TOK / 512, NE), 256, 0, stream>>>(scoresT, hist);
    scan16_kernel<<<NE, 256, 0, stream>>>(hist, prefix16, G16, rem);
    fill_collect_kernel<<<dim3(N_TOK / 256, NE), 256, 0, stream>>>(
        scoresT, prefix16, cnt, candcnt, idx, scale, candbuf);
    cand_rank_kernel<<<NE, 256, 0, stream>>>(prefix16, G16, rem, candcnt, candbuf, idx, scale);

    // w1 -> rows [0,2048) of w13T; w3 -> rows [2048,4096); w2 -> w2T
    transpose_convert_kernel<<<dim3(DIM / 64, HID / 64, NE), 256, 0, stream>>>(
        w1, w13T, DIM, HID, W13_STRIDE);
    transpose_convert_kernel<<<dim3(DIM / 64, HID / 64, NE), 256, 0, stream>>>(
        w3, w13T + (size_t)HID * DIM, DIM, HID, W13_STRIDE);
    transpose_convert_kernel<<<dim3(HID / 64, DIM / 64, NE), 256, 0, stream>>>(
        w2, w2T, HID, DIM, (size_t)DIM * HID);

    for (int e = 0; e < NE; ++e) {
        gather_rows_kernel<<<CAP, 256, 0, stream>>>(x, idx + e * CAP, scale + e * CAP, Ae);
        // G(4096 x 4096) = Ae @ [W1;W3]^T
        gemm_bt_kernel<0><<<dim3(CAP / 128, (2 * HID) / 128), 256, 0, stream>>>(
            Ae, w13T + (size_t)e * W13_STRIDE, G, nullptr, nullptr,
            CAP, 2 * HID, DIM, DIM);
        // left half of G <- silu(G1) * G3
        swiglu_kernel<<<(CAP * (HID / 8)) / 256, 256, 0, stream>>>(G);
        // out[token] += H @ W2^T  (H = left half of G, lda = 4096)
        gemm_bt_kernel<1><<<dim3(CAP / 128, DIM / 128), 256, 0, stream>>>(
            G, w2T + (size_t)e * DIM * HID, nullptr, out, idx + e * CAP,
            CAP, DIM, HID, 2 * HID);
    }
}

// Round 4
// 1267.775 us; speedup vs baseline: 1.4336x; 1.0558x over previous
//
#include <hip/hip_runtime.h>

typedef __attribute__((ext_vector_type(4))) float f32x4;
typedef __attribute__((ext_vector_type(8))) _Float16 f16x8;
typedef __attribute__((ext_vector_type(4))) _Float16 f16x4;

#define N_TOK 16384
#define DIM 1024
#define HID 2048
#define NE 8
#define CAP 4096

// async global->LDS, 16B per lane; LDS dest is wave-uniform base + lane*16
#define GLD_LDS16(gaddr, laddr)                                                   \
    __builtin_amdgcn_global_load_lds(                                             \
        (const __attribute__((address_space(1))) void*)(gaddr),                   \
        (__attribute__((address_space(3))) void*)(laddr), 16, 0, 0)

// ---------------- Router: scores^T (E, N) = softmax(x @ wg, axis=-1)^T -------
__global__ __launch_bounds__(256) void router_kernel(
    const float* __restrict__ x, const float* __restrict__ wg,
    float* __restrict__ scoresT)
{
    int t = blockIdx.x * 4 + (threadIdx.x >> 6);
    int lane = threadIdx.x & 63;
    const float* xr = x + (size_t)t * DIM;
    float acc[NE] = {};
    for (int k = lane; k < DIM; k += 64) {
        float xv = xr[k];
        const float4* w4 = (const float4*)(wg + (size_t)k * NE);
        float4 a = w4[0], b = w4[1];
        acc[0] += xv * a.x; acc[1] += xv * a.y; acc[2] += xv * a.z; acc[3] += xv * a.w;
        acc[4] += xv * b.x; acc[5] += xv * b.y; acc[6] += xv * b.z; acc[7] += xv * b.w;
    }
#pragma unroll
    for (int off = 32; off; off >>= 1)
#pragma unroll
        for (int e = 0; e < NE; ++e) acc[e] += __shfl_xor(acc[e], off);
    if (lane == 0) {
        float m = acc[0];
#pragma unroll
        for (int e = 1; e < NE; ++e) m = fmaxf(m, acc[e]);
        float p[NE]; float s = 0.f;
#pragma unroll
        for (int e = 0; e < NE; ++e) { p[e] = expf(acc[e] - m); s += p[e]; }
        float inv = 1.0f / s;
#pragma unroll
        for (int e = 0; e < NE; ++e) scoresT[(size_t)e * N_TOK + t] = p[e] * inv;
    }
}

// ---- Top-k pass 1: global 65536-bin histogram of top-16 key bits ----------
__global__ __launch_bounds__(256) void hist16_kernel(
    const float* __restrict__ scoresT, int* __restrict__ hist)
{
    int e = blockIdx.y;
    int t = blockIdx.x * 512 + threadIdx.x;
    const float* row = scoresT + (size_t)e * N_TOK;
    int* h = hist + (size_t)e * 65536;
#pragma unroll
    for (int i = 0; i < 2; ++i) {
        unsigned key = __float_as_uint(row[t + i * 256]);
        atomicAdd(&h[key >> 16], 1);
    }
}

// ---- Top-k pass 2: find threshold bin, strictly-above count, remaining ----
__global__ __launch_bounds__(256) void scan16_kernel(
    const int* __restrict__ hist, unsigned* __restrict__ prefix16,
    int* __restrict__ G16, int* __restrict__ rem)
{
    int e = blockIdx.x;
    const int* h = hist + (size_t)e * 65536;
    __shared__ int sums[256];
    __shared__ int bins[256];
    __shared__ int s_c, s_cum;
    int t = threadIdx.x;
    int s = 0;
    for (int b = 0; b < 256; ++b) s += h[t * 256 + b];
    sums[t] = s;
    __syncthreads();
    if (t == 0) {
        int cum = 0; int c = 255;
        for (; c >= 0; --c) {
            if (cum + sums[c] >= CAP) break;
            cum += sums[c];
        }
        s_c = c; s_cum = cum;
    }
    __syncthreads();
    bins[t] = h[s_c * 256 + t];
    __syncthreads();
    if (t == 0) {
        int cum = s_cum; int b = 255;
        for (; b >= 0; --b) {
            if (cum + bins[b] >= CAP) break;
            cum += bins[b];
        }
        prefix16[e] = (unsigned)(s_c * 256 + b);
        G16[e] = cum;            // strictly above threshold bin
        rem[e] = CAP - cum;      // to take from within the bin
    }
}

// ---- Top-k pass 3: fill strictly-above (order-free) + collect bin members -
__global__ __launch_bounds__(256) void fill_collect_kernel(
    const float* __restrict__ scoresT, const unsigned* __restrict__ prefix16,
    int* __restrict__ cnt, int* __restrict__ candcnt,
    int* __restrict__ idx, float* __restrict__ scale, unsigned* __restrict__ candbuf)
{
    int t = blockIdx.x * 256 + threadIdx.x;
    int e = blockIdx.y;
    float s = scoresT[(size_t)e * N_TOK + t];
    unsigned hi = __float_as_uint(s) >> 16;
    unsigned p16 = prefix16[e];
    if (hi > p16) {
        int pos = atomicAdd(&cnt[e], 1);
        idx[e * CAP + pos] = t;
        scale[e * CAP + pos] = s;
    } else if (hi == p16) {
        int pos = atomicAdd(&candcnt[e], 1);
        // descending order of packed = key desc, then token asc (top_k ties)
        candbuf[(size_t)e * N_TOK + pos] =
            ((__float_as_uint(s) & 0xFFFFu) << 16) | (unsigned)(16383 - t);
    }
}

// ---- Top-k pass 4: rank in-bin candidates, keep top `rem` ------------------
__global__ __launch_bounds__(256) void cand_rank_kernel(
    const unsigned* __restrict__ prefix16, const int* __restrict__ G16,
    const int* __restrict__ rem, const int* __restrict__ candcnt,
    const unsigned* __restrict__ candbuf, int* __restrict__ idx, float* __restrict__ scale)
{
    int e = blockIdx.x;
    int Tc = candcnt[e], q = rem[e], g = G16[e];
    const unsigned* cb = candbuf + (size_t)e * N_TOK;
    for (int i = threadIdx.x; i < Tc; i += 256) {
        unsigned mine = cb[i];
        int rank = 0;
        for (int j = 0; j < Tc; ++j) rank += (cb[j] > mine) ? 1 : 0;
        if (rank < q) {
            int token = 16383 - (int)(mine & 0xFFFFu);
            unsigned keyfull = (prefix16[e] << 16) | (mine >> 16);
            idx[e * CAP + g + rank] = token;
            scale[e * CAP + g + rank] = __uint_as_float(keyfull);
        }
    }
}

// -------- Weight transpose+convert: (E,K,N) f32 -> rows at WT+e*ostride+n*K -
__global__ __launch_bounds__(256) void transpose_convert_kernel(
    const float* __restrict__ W, _Float16* __restrict__ WT, int K, int N,
    size_t ostride)
{
    int e = blockIdx.z;
    int k0 = blockIdx.x * 64;
    int n0 = blockIdx.y * 64;
    __shared__ float tile[64][65];
    const float* Wb = W + (size_t)e * K * N;
    _Float16* WTb = WT + (size_t)e * ostride;
#pragma unroll
    for (int i = 0; i < 16; ++i) {
        int lin = i * 256 + threadIdx.x;
        int r = lin >> 6, c = lin & 63;
        tile[r][c] = Wb[(size_t)(k0 + r) * N + n0 + c];
    }
    __syncthreads();
#pragma unroll
    for (int i = 0; i < 16; ++i) {
        int lin = i * 256 + threadIdx.x;
        int r = lin >> 6, c = lin & 63;   // r: n-offset, c: k-offset
        WTb[(size_t)(n0 + r) * K + k0 + c] = (_Float16)tile[c][r];
    }
}

// ---- Gather + scale + convert, batched: blockIdx.y = expert-in-group -------
__global__ __launch_bounds__(256) void gather_rows_kernel(
    const float* __restrict__ x, const int* __restrict__ idx,
    const float* __restrict__ scale, _Float16* __restrict__ Ae, int e0)
{
    int ez = blockIdx.y;
    int c = blockIdx.x;
    int token = idx[(e0 + ez) * CAP + c];
    float sc = scale[(e0 + ez) * CAP + c];
    const float4* xr = (const float4*)(x + (size_t)token * DIM);
    float4 v = xr[threadIdx.x];
    f16x4 h;
    h[0] = (_Float16)(v.x * sc); h[1] = (_Float16)(v.y * sc);
    h[2] = (_Float16)(v.z * sc); h[3] = (_Float16)(v.w * sc);
    *(f16x4*)(Ae + ((size_t)ez * CAP + c) * DIM + threadIdx.x * 4) = h;
}

// ---- GEMM13 + SwiGLU fused: H = silu(A@W1^T) * (A@W3^T), f16 out -----------
// A panel shared by both B panels; silu applied on fp32 accumulators.
__global__ __launch_bounds__(256) void gemm13_swiglu_kernel(
    const _Float16* __restrict__ Ae, const _Float16* __restrict__ w13T,
    _Float16* __restrict__ H, int e0)
{
    __shared__ _Float16 As[128 * 64];
    __shared__ _Float16 B1s[128 * 64];
    __shared__ _Float16 B3s[128 * 64];
    const int ez = blockIdx.z;
    const _Float16* A = Ae + (size_t)ez * CAP * DIM;
    const _Float16* B = w13T + (size_t)(e0 + ez) * (2 * HID * DIM);
    const int bm = blockIdx.x * 128;
    const int bn = blockIdx.y * 128;                 // col within [0,HID)
    const int tid = threadIdx.x;
    const int wave = tid >> 6, lane = tid & 63;
    const int wm = (wave >> 1) * 64, wn = (wave & 1) * 64;
    const int lr = lane >> 3;                        // 0..7
    const int lcs = ((lane & 7) ^ lr) * 8;           // XOR-swizzled col start

    f32x4 acc1[4][4] = {};
    f32x4 acc3[4][4] = {};
    const int row16 = lane & 15;
    const int qi = lane >> 4;
    const int r7 = row16 & 7;

    const _Float16* gA  = A + (size_t)(bm + wave * 32 + lr) * DIM + lcs;
    const _Float16* gB1 = B + (size_t)(bn + wave * 32 + lr) * DIM + lcs;
    const _Float16* gB3 = B + (size_t)(HID + bn + wave * 32 + lr) * DIM + lcs;
    _Float16* lA  = As  + (wave * 32) * 64;
    _Float16* lB1 = B1s + (wave * 32) * 64;
    _Float16* lB3 = B3s + (wave * 32) * 64;

    for (int k0 = 0; k0 < DIM; k0 += 64) {
        __syncthreads();
#pragma unroll
        for (int i = 0; i < 4; ++i) {
            GLD_LDS16(gA  + (size_t)i * 8 * DIM + k0, lA  + i * 8 * 64);
            GLD_LDS16(gB1 + (size_t)i * 8 * DIM + k0, lB1 + i * 8 * 64);
            GLD_LDS16(gB3 + (size_t)i * 8 * DIM + k0, lB3 + i * 8 * 64);
        }
        __syncthreads();
#pragma unroll
        for (int ks = 0; ks < 64; ks += 32) {
            const int kc = ks >> 3;
            f16x8 af[4], bf[4];
#pragma unroll
            for (int i = 0; i < 4; ++i) {
                int cg = ((kc + qi) ^ r7) << 3;
                af[i] = *(const f16x8*)(&As[(wm + i * 16 + row16) * 64 + cg]);
                bf[i] = *(const f16x8*)(&B1s[(wn + i * 16 + row16) * 64 + cg]);
            }
#pragma unroll
            for (int i = 0; i < 4; ++i)
#pragma unroll
                for (int j = 0; j < 4; ++j)
                    acc1[i][j] = __builtin_amdgcn_mfma_f32_16x16x32_f16(
                        af[i], bf[j], acc1[i][j], 0, 0, 0);
#pragma unroll
            for (int i = 0; i < 4; ++i) {
                int cg = ((kc + qi) ^ r7) << 3;
                bf[i] = *(const f16x8*)(&B3s[(wn + i * 16 + row16) * 64 + cg]);
            }
#pragma unroll
            for (int i = 0; i < 4; ++i)
#pragma unroll
                for (int j = 0; j < 4; ++j)
                    acc3[i][j] = __builtin_amdgcn_mfma_f32_16x16x32_f16(
                        af[i], bf[j], acc3[i][j], 0, 0, 0);
        }
    }

    _Float16* Hc = H + (size_t)ez * CAP * HID;
    const int col0 = lane & 15;
    const int r0 = (lane >> 4) * 4;
#pragma unroll
    for (int i = 0; i < 4; ++i)
#pragma unroll
        for (int r = 0; r < 4; ++r) {
            int row = bm + wm + i * 16 + r0 + r;
#pragma unroll
            for (int j = 0; j < 4; ++j) {
                int col = bn + wn + j * 16 + col0;
                float g1 = acc1[i][j][r];
                float g3 = acc3[i][j][r];
                float sv = g1 / (1.0f + __expf(-g1)) * g3;
                Hc[(size_t)row * HID + col] = (_Float16)sv;
            }
        }
}

// ---- GEMM2 + scatter: out[token] += H @ W2^T (fp32 atomics) ----------------
__global__ __launch_bounds__(256) void gemm2_scatter_kernel(
    const _Float16* __restrict__ H, const _Float16* __restrict__ w2T,
    float* __restrict__ out, const int* __restrict__ idx, int e0)
{
    __shared__ _Float16 As[128 * 64];
    __shared__ _Float16 Bs[128 * 64];
    const int ez = blockIdx.z;
    const _Float16* A = H + (size_t)ez * CAP * HID;
    const _Float16* Bt = w2T + (size_t)(e0 + ez) * DIM * HID;
    const int* rowidx = idx + (e0 + ez) * CAP;
    const int bm = blockIdx.x * 128;
    const int bn = blockIdx.y * 128;
    const int tid = threadIdx.x;
    const int wave = tid >> 6, lane = tid & 63;
    const int wm = (wave >> 1) * 64, wn = (wave & 1) * 64;
    const int lr = lane >> 3;
    const int lcs = ((lane & 7) ^ lr) * 8;

    f32x4 acc[4][4] = {};
    const int row16 = lane & 15;
    const int qi = lane >> 4;
    const int r7 = row16 & 7;

    const _Float16* gA = A + (size_t)(bm + wave * 32 + lr) * HID + lcs;
    const _Float16* gB = Bt + (size_t)(bn + wave * 32 + lr) * HID + lcs;
    _Float16* lA = As + (wave * 32) * 64;
    _Float16* lB = Bs + (wave * 32) * 64;

    for (int k0 = 0; k0 < HID; k0 += 64) {
        __syncthreads();
#pragma unroll
        for (int i = 0; i < 4; ++i) {
            GLD_LDS16(gA + (size_t)i * 8 * HID + k0, lA + i * 8 * 64);
            GLD_LDS16(gB + (size_t)i * 8 * HID + k0, lB + i * 8 * 64);
        }
        __syncthreads();
#pragma unroll
        for (int ks = 0; ks < 64; ks += 32) {
            const int kc = ks >> 3;
            f16x8 af[4], bf[4];
#pragma unroll
            for (int i = 0; i < 4; ++i) {
                int cg = ((kc + qi) ^ r7) << 3;
                af[i] = *(const f16x8*)(&As[(wm + i * 16 + row16) * 64 + cg]);
                bf[i] = *(const f16x8*)(&Bs[(wn + i * 16 + row16) * 64 + cg]);
            }
#pragma unroll
            for (int i = 0; i < 4; ++i)
#pragma unroll
                for (int j = 0; j < 4; ++j)
                    acc[i][j] = __builtin_amdgcn_mfma_f32_16x16x32_f16(
                        af[i], bf[j], acc[i][j], 0, 0, 0);
        }
    }

    const int col0 = lane & 15;
    const int r0 = (lane >> 4) * 4;
#pragma unroll
    for (int i = 0; i < 4; ++i)
#pragma unroll
        for (int r = 0; r < 4; ++r) {
            int row = bm + wm + i * 16 + r0 + r;
            int token = rowidx[row];
#pragma unroll
            for (int j = 0; j < 4; ++j) {
                int col = bn + wn + j * 16 + col0;
                atomicAdd(&out[(size_t)token * DIM + col], acc[i][j][r]);
            }
        }
}

extern "C" void kernel_launch(void* const* d_in, const int* in_sizes, int n_in,
                              void* d_out, int out_size, void* d_ws, size_t ws_size,
                              hipStream_t stream)
{
    const float* x  = (const float*)d_in[0];
    const float* wg = (const float*)d_in[1];
    const float* w1 = (const float*)d_in[2];
    const float* w3 = (const float*)d_in[3];
    const float* w2 = (const float*)d_in[4];
    float* out = (float*)d_out;

    char* ws = (char*)d_ws;
    size_t off = 0;
    auto alloc = [&](size_t bytes) -> void* {
        void* p = ws + off;
        off += (bytes + 255) & ~(size_t)255;
        return p;
    };
    float*     scoresT  = (float*)alloc((size_t)NE * N_TOK * 4);
    int*       hist     = (int*)alloc((size_t)NE * 65536 * 4);     // 2 MB
    unsigned*  prefix16 = (unsigned*)alloc(256);
    int*       G16      = (int*)alloc(256);
    int*       rem      = (int*)alloc(256);
    int*       counters = (int*)alloc(256);      // [0..7]=cnt, [8..15]=candcnt
    int*       idx      = (int*)alloc((size_t)NE * CAP * 4);
    float*     scale    = (float*)alloc((size_t)NE * CAP * 4);
    unsigned*  candbuf  = (unsigned*)alloc((size_t)NE * N_TOK * 4);
    _Float16*  w13T     = (_Float16*)alloc((size_t)NE * 2 * HID * DIM * 2); // 64 MB
    _Float16*  w2T      = (_Float16*)alloc((size_t)NE * DIM * HID * 2);     // 32 MB
    int* cnt = counters;
    int* candcnt = counters + 8;
    const size_t W13_STRIDE = (size_t)2 * HID * DIM;   // per-expert, halves

    // Group size: largest g in {8,4,2,1} whose Ae+H buffers fit in remaining ws.
    // Constant given ws_size -> identical work every call (capture-safe).
    size_t per_expert = ((size_t)CAP * DIM * 2) + ((size_t)CAP * HID * 2); // 24 MB
    int g = 8;
    while (g > 1 && off + (size_t)g * per_expert > ws_size) g >>= 1;
    _Float16* Ae = (_Float16*)alloc((size_t)g * CAP * DIM * 2);
    _Float16* H  = (_Float16*)alloc((size_t)g * CAP * HID * 2);

    hipMemsetAsync(d_out, 0, (size_t)out_size * 4, stream);
    hipMemsetAsync(counters, 0, 256, stream);
    hipMemsetAsync(hist, 0, (size_t)NE * 65536 * 4, stream);

    router_kernel<<<N_TOK / 4, 256, 0, stream>>>(x, wg, scoresT);
    hist16_kernel<<<dim3(N_TOK / 512, NE), 256, 0, stream>>>(scoresT, hist);
    scan16_kernel<<<NE, 256, 0, stream>>>(hist, prefix16, G16, rem);
    fill_collect_kernel<<<dim3(N_TOK / 256, NE), 256, 0, stream>>>(
        scoresT, prefix16, cnt, candcnt, idx, scale, candbuf);
    cand_rank_kernel<<<NE, 256, 0, stream>>>(prefix16, G16, rem, candcnt, candbuf, idx, scale);

    // w1 -> rows [0,2048) of w13T; w3 -> rows [2048,4096); w2 -> w2T
    transpose_convert_kernel<<<dim3(DIM / 64, HID / 64, NE), 256, 0, stream>>>(
        w1, w13T, DIM, HID, W13_STRIDE);
    transpose_convert_kernel<<<dim3(DIM / 64, HID / 64, NE), 256, 0, stream>>>(
        w3, w13T + (size_t)HID * DIM, DIM, HID, W13_STRIDE);
    transpose_convert_kernel<<<dim3(HID / 64, DIM / 64, NE), 256, 0, stream>>>(
        w2, w2T, HID, DIM, (size_t)DIM * HID);

    for (int e0 = 0; e0 < NE; e0 += g) {
        gather_rows_kernel<<<dim3(CAP, g), 256, 0, stream>>>(x, idx, scale, Ae, e0);
        gemm13_swiglu_kernel<<<dim3(CAP / 128, HID / 128, g), 256, 0, stream>>>(
            Ae, w13T, H, e0);
        gemm2_scatter_kernel<<<dim3(CAP / 128, DIM / 128, g), 256, 0, stream>>>(
            H, w2T, out, idx, e0);
    }
}